// Round 5
// baseline (475.996 us; speedup 1.0000x reference)
//
#include <hip/hip_runtime.h>
#include <hip/hip_cooperative_groups.h>
#include <math.h>

namespace cg = cooperative_groups;

#define C_CLASSES 100000
#define FEAT      512
#define BATCH_N   32768
#define EPS_N     1e-12f

// Phases: 0 = centers stream (normalize-accumulate + copy out)
//         1 = cpart -> partial2 (32 blocks)
//         2 = mean in LDS, single x pass (ssx, x.mean, x.c_lab, ssc) -> lpart
//         3 = final reduce + epoch blend -> out[0]
// coop==1: one launch, grid.sync() between phases. coop==0: sliced launches.
__global__ void __launch_bounds__(256) rdc_coop(
    const float* __restrict__ x,
    const int*   __restrict__ labels,
    const int*   __restrict__ epoch,
    const float* __restrict__ centers,
    float*       __restrict__ out,        // [0] loss, [1..] centers copy
    float*       __restrict__ cpart,      // [grid * 512]
    float*       __restrict__ partial2,   // [32 * 512]
    float*       __restrict__ lpart,      // [grid * 2]
    int phase_lo, int phase_hi, int coop)
{
    const int t   = threadIdx.x;
    const int wid = t >> 6;
    const int ln  = t & 63;
    const int bid = blockIdx.x;
    const int nb  = gridDim.x;

    __shared__ float accsh[4][FEAT];
    __shared__ float mean_sh[FEAT];
    __shared__ float redsh[2][4];
    __shared__ double dsh1[256];
    __shared__ double dsh2[256];

    // ---------------- Phase 0: centers stream ----------------
    if (phase_lo <= 0 && 0 < phase_hi) {
        float4 a0 = make_float4(0.f,0.f,0.f,0.f);
        float4 a1 = make_float4(0.f,0.f,0.f,0.f);
        float* outc = out + 1;

        for (int row = bid * 4 + wid; row < C_CLASSES; row += nb * 4) {
            const float4* rp = reinterpret_cast<const float4*>(centers + (size_t)row * FEAT);
            const float4 v0 = rp[ln];
            const float4 v1 = rp[ln + 64];

            float ss = v0.x*v0.x + v0.y*v0.y + v0.z*v0.z + v0.w*v0.w
                     + v1.x*v1.x + v1.y*v1.y + v1.z*v1.z + v1.w*v1.w;
            #pragma unroll
            for (int o = 32; o > 0; o >>= 1) ss += __shfl_xor(ss, o, 64);

            const float rn = 1.f / fmaxf(sqrtf(ss), EPS_N);
            a0.x += v0.x * rn; a0.y += v0.y * rn; a0.z += v0.z * rn; a0.w += v0.w * rn;
            a1.x += v1.x * rn; a1.y += v1.y * rn; a1.z += v1.z * rn; a1.w += v1.w * rn;

            float* op = outc + (size_t)row * FEAT;
            op[4*ln + 0] = v0.x; op[4*ln + 1] = v0.y;
            op[4*ln + 2] = v0.z; op[4*ln + 3] = v0.w;
            op[256 + 4*ln + 0] = v1.x; op[256 + 4*ln + 1] = v1.y;
            op[256 + 4*ln + 2] = v1.z; op[256 + 4*ln + 3] = v1.w;
        }

        accsh[wid][4*ln + 0] = a0.x; accsh[wid][4*ln + 1] = a0.y;
        accsh[wid][4*ln + 2] = a0.z; accsh[wid][4*ln + 3] = a0.w;
        accsh[wid][256 + 4*ln + 0] = a1.x; accsh[wid][256 + 4*ln + 1] = a1.y;
        accsh[wid][256 + 4*ln + 2] = a1.z; accsh[wid][256 + 4*ln + 3] = a1.w;
        __syncthreads();

        #pragma unroll
        for (int j = t; j < FEAT; j += 256)
            cpart[(size_t)bid * FEAT + j] =
                accsh[0][j] + accsh[1][j] + accsh[2][j] + accsh[3][j];
    }

    if (coop && phase_lo <= 0 && 1 < phase_hi) cg::this_grid().sync();

    // ---------------- Phase 1: cpart -> partial2 (blocks 0..31) ----------------
    if (phase_lo <= 1 && 1 < phase_hi) {
        if (bid < 32) {
            for (int j = t; j < FEAT; j += 256) {
                float s = 0.f;
                for (int b = bid; b < nb; b += 32)
                    s += cpart[(size_t)b * FEAT + j];
                partial2[(size_t)bid * FEAT + j] = s;
            }
        }
    }

    if (coop && phase_lo <= 1 && 2 < phase_hi) cg::this_grid().sync();

    // ---------------- Phase 2: mean + single x pass ----------------
    if (phase_lo <= 2 && 2 < phase_hi) {
        for (int j = t; j < FEAT; j += 256) {
            float s = 0.f;
            #pragma unroll
            for (int p = 0; p < 32; ++p) s += partial2[(size_t)p * FEAT + j];
            mean_sh[j] = s * (1.f / (float)C_CLASSES);
        }
        __syncthreads();

        const float4 mv0 = *reinterpret_cast<const float4*>(&mean_sh[4*ln]);
        const float4 mv1 = *reinterpret_cast<const float4*>(&mean_sh[256 + 4*ln]);

        float t1acc = 0.f, t2acc = 0.f;
        const float kC = (float)((double)(C_CLASSES + 1) / (double)C_CLASSES);

        for (int row = bid * 4 + wid; row < BATCH_N; row += nb * 4) {
            const float4* xr = reinterpret_cast<const float4*>(x + (size_t)row * FEAT);
            const int lab = labels[row];
            const float4* cr = reinterpret_cast<const float4*>(centers + (size_t)lab * FEAT);

            const float4 xv0 = xr[ln], xv1 = xr[ln + 64];
            const float4 cv0 = cr[ln], cv1 = cr[ln + 64];

            float ssx = xv0.x*xv0.x + xv0.y*xv0.y + xv0.z*xv0.z + xv0.w*xv0.w
                      + xv1.x*xv1.x + xv1.y*xv1.y + xv1.z*xv1.z + xv1.w*xv1.w;
            float dxm = xv0.x*mv0.x + xv0.y*mv0.y + xv0.z*mv0.z + xv0.w*mv0.w
                      + xv1.x*mv1.x + xv1.y*mv1.y + xv1.z*mv1.z + xv1.w*mv1.w;
            float dxc = xv0.x*cv0.x + xv0.y*cv0.y + xv0.z*cv0.z + xv0.w*cv0.w
                      + xv1.x*cv1.x + xv1.y*cv1.y + xv1.z*cv1.z + xv1.w*cv1.w;
            float ssc = cv0.x*cv0.x + cv0.y*cv0.y + cv0.z*cv0.z + cv0.w*cv0.w
                      + cv1.x*cv1.x + cv1.y*cv1.y + cv1.z*cv1.z + cv1.w*cv1.w;

            #pragma unroll
            for (int o = 32; o > 0; o >>= 1) {
                ssx += __shfl_xor(ssx, o, 64);
                dxm += __shfl_xor(dxm, o, 64);
                dxc += __shfl_xor(dxc, o, 64);
                ssc += __shfl_xor(ssc, o, 64);
            }

            if (ln == 0) {
                const float rnx = 1.f / fmaxf(sqrtf(ssx), EPS_N);
                const float rnc = 1.f / fmaxf(sqrtf(ssc), EPS_N);
                const float s_all = dxm * rnx;
                const float s_lab = dxc * rnx * rnc;
                const float e_all = expf(s_all);
                t1acc += (e_all - expf(s_lab * kC));                      // / ALPHA1 (=1)
                t2acc += -fabsf((e_all - expf(s_lab) + 0.2f) * (1.f / 50.f));
            }
        }

        if (ln == 0) { redsh[0][wid] = t1acc; redsh[1][wid] = t2acc; }
        __syncthreads();
        if (t == 0) {
            lpart[(size_t)bid * 2]     = redsh[0][0] + redsh[0][1] + redsh[0][2] + redsh[0][3];
            lpart[(size_t)bid * 2 + 1] = redsh[1][0] + redsh[1][1] + redsh[1][2] + redsh[1][3];
        }
    }

    if (coop && phase_lo <= 2 && 3 < phase_hi) cg::this_grid().sync();

    // ---------------- Phase 3: final reduce + blend ----------------
    if (phase_lo <= 3 && 3 < phase_hi) {
        if (bid == 0) {
            double s1 = 0.0, s2 = 0.0;
            for (int i = t; i < nb; i += 256) {
                s1 += (double)lpart[(size_t)i * 2];
                s2 += (double)lpart[(size_t)i * 2 + 1];
            }
            dsh1[t] = s1;
            dsh2[t] = s2;
            __syncthreads();
            for (int s = 128; s > 0; s >>= 1) {
                if (t < s) { dsh1[t] += dsh1[t + s]; dsh2[t] += dsh2[t + s]; }
                __syncthreads();
            }
            if (t == 0) {
                const float v  = fminf((float)(*epoch) * (1.f / 14.f), 1.f);
                const float l1 = (float)(dsh1[0] / (double)BATCH_N);
                const float l2 = (float)(dsh2[0] / (double)BATCH_N);
                out[0] = (1.f - v) * l1 + v * l2;
            }
        }
    }
}

extern "C" void kernel_launch(void* const* d_in, const int* in_sizes, int n_in,
                              void* d_out, int out_size, void* d_ws, size_t ws_size,
                              hipStream_t stream)
{
    const float* x       = (const float*)d_in[0];
    const int*   labels  = (const int*)d_in[1];
    // d_in[2] = ori_labels (unused by reference)
    const int*   epoch   = (const int*)d_in[3];
    const float* centers = (const float*)d_in[4];
    float* out = (float*)d_out;

    float* ws       = (float*)d_ws;
    float* partial2 = ws;                 // 32*512
    float* lpart    = ws + 16384;         // grid*2 (<= 4096)
    float* cpart    = ws + 16384 + 8192;  // grid*512 (<= 1 M floats)

    // Max co-resident grid for cooperative launch.
    int maxb = 0;
    hipError_t oe = hipOccupancyMaxActiveBlocksPerMultiprocessor(&maxb, rdc_coop, 256, 0);
    if (oe != hipSuccess || maxb < 1) maxb = 4;
    int grid = maxb * 256;
    if (grid > 2048) grid = 2048;
    if (grid < 64)   grid = 64;

    int pl0 = 0, ph4 = 4, coop1 = 1;
    void* args[] = {
        (void*)&x, (void*)&labels, (void*)&epoch, (void*)&centers,
        (void*)&out, (void*)&cpart, (void*)&partial2, (void*)&lpart,
        (void*)&pl0, (void*)&ph4, (void*)&coop1
    };
    hipError_t le = hipLaunchCooperativeKernel((const void*)rdc_coop,
                                               dim3(grid), dim3(256), args, 0, stream);
    if (le != hipSuccess) {
        // Fallback: phase-sliced normal launches (same kernel, no grid.sync).
        rdc_coop<<<grid, 256, 0, stream>>>(x, labels, epoch, centers, out,
                                           cpart, partial2, lpart, 0, 1, 0);
        rdc_coop<<<grid, 256, 0, stream>>>(x, labels, epoch, centers, out,
                                           cpart, partial2, lpart, 1, 2, 0);
        rdc_coop<<<grid, 256, 0, stream>>>(x, labels, epoch, centers, out,
                                           cpart, partial2, lpart, 2, 3, 0);
        rdc_coop<<<grid, 256, 0, stream>>>(x, labels, epoch, centers, out,
                                           cpart, partial2, lpart, 3, 4, 0);
    }
}

// Round 6
// 135.127 us; speedup vs baseline: 3.5226x; 3.5226x over previous
//
#include <hip/hip_runtime.h>
#include <math.h>

#define C_CLASSES 100000
#define FEAT      512
#define BATCH_N   32768
#define EPS_N     1e-12f

// ---------------- Kernel A: wave-per-4-rows normalize-accumulate + copy-out ----------------
// Batched burst pattern: each wave owns 4 consecutive rows per iteration.
// 32 global loads issued back-to-back (deep read burst), then 4 interleaved
// shuffle-reduce chains (ILP), then 32 stores back-to-back (write burst).
// Reduces R/W turnaround vs the row-at-a-time version.
__global__ void __launch_bounds__(256) centers_pass(
    const float* __restrict__ centers,
    float* __restrict__ out_centers,   // d_out + 1
    float* __restrict__ cpart,         // [gridDim.x * 512]
    float* __restrict__ rnorms)        // [C_CLASSES]
{
    const int t   = threadIdx.x;
    const int wid = t >> 6;
    const int ln  = t & 63;
    const int nb  = gridDim.x;

    float acc[8] = {0.f,0.f,0.f,0.f,0.f,0.f,0.f,0.f};

    // Each wave handles rows [b0, b0+4) per iteration.
    for (int b0 = (blockIdx.x * 4 + wid) * 4; b0 < C_CLASSES; b0 += nb * 16) {
        const int nr = (b0 + 4 <= C_CLASSES) ? 4 : (C_CLASSES - b0);

        float v[4][8];
        #pragma unroll
        for (int r = 0; r < 4; ++r) {
            if (r < nr) {
                const float* rp = centers + (size_t)(b0 + r) * FEAT;
                #pragma unroll
                for (int k = 0; k < 8; ++k) v[r][k] = rp[ln + 64 * k];
            } else {
                #pragma unroll
                for (int k = 0; k < 8; ++k) v[r][k] = 0.f;
            }
        }

        float ss[4];
        #pragma unroll
        for (int r = 0; r < 4; ++r) {
            ss[r] = 0.f;
            #pragma unroll
            for (int k = 0; k < 8; ++k) ss[r] += v[r][k] * v[r][k];
        }
        // 4 independent butterfly chains, interleaved for ILP
        #pragma unroll
        for (int o = 32; o > 0; o >>= 1) {
            #pragma unroll
            for (int r = 0; r < 4; ++r) ss[r] += __shfl_xor(ss[r], o, 64);
        }

        float rn[4];
        #pragma unroll
        for (int r = 0; r < 4; ++r) rn[r] = 1.f / fmaxf(sqrtf(ss[r]), EPS_N);

        if (ln == 0) {
            #pragma unroll
            for (int r = 0; r < 4; ++r)
                if (r < nr) rnorms[b0 + r] = rn[r];
        }

        #pragma unroll
        for (int r = 0; r < 4; ++r)
            #pragma unroll
            for (int k = 0; k < 8; ++k) acc[k] += v[r][k] * rn[r];

        #pragma unroll
        for (int r = 0; r < 4; ++r) {
            if (r < nr) {
                float* op = out_centers + (size_t)(b0 + r) * FEAT;
                #pragma unroll
                for (int k = 0; k < 8; ++k) op[ln + 64 * k] = v[r][k];
            }
        }
    }

    __shared__ float accsh[4][FEAT];
    #pragma unroll
    for (int k = 0; k < 8; ++k) accsh[wid][ln + 64 * k] = acc[k];
    __syncthreads();

    #pragma unroll
    for (int j = t; j < FEAT; j += 256)
        cpart[(size_t)blockIdx.x * FEAT + j] =
            accsh[0][j] + accsh[1][j] + accsh[2][j] + accsh[3][j];
}

// ---------------- Kernel B1: parallel partial reduce over cpart blocks ----------------
__global__ void __launch_bounds__(512) reduce_mean_s1(
    const float* __restrict__ cpart, int nblk,
    float* __restrict__ partial2)
{
    const int j = threadIdx.x;             // feature
    float s = 0.f;
    for (int b = blockIdx.x; b < nblk; b += gridDim.x)
        s += cpart[(size_t)b * FEAT + j];
    partial2[(size_t)blockIdx.x * FEAT + j] = s;
}

// ---------------- Kernel B2: finish -> mean[512] ----------------
__global__ void __launch_bounds__(512) reduce_mean_s2(
    const float* __restrict__ partial2, int np,
    float* __restrict__ mean)
{
    const int j = threadIdx.x;
    float s = 0.f;
    for (int p = 0; p < np; ++p)
        s += partial2[(size_t)p * FEAT + j];
    mean[j] = s / (float)C_CLASSES;
}

// ---------------- Kernel C: per-x-row loss terms (one wave per row) ----------------
__global__ void __launch_bounds__(256) row_loss(
    const float* __restrict__ x,
    const int*   __restrict__ labels,
    const float* __restrict__ centers,
    const float* __restrict__ mean,
    const float* __restrict__ rnorms,
    float* __restrict__ lpart)          // [gridDim.x * 2]
{
    const int wid = threadIdx.x >> 6;
    const int ln  = threadIdx.x & 63;
    const int row = blockIdx.x * 4 + wid;

    const float4* __restrict__ xr = reinterpret_cast<const float4*>(x + (size_t)row * FEAT);
    const float4* __restrict__ mr = reinterpret_cast<const float4*>(mean);
    const int lab = labels[row];
    const float4* __restrict__ cr = reinterpret_cast<const float4*>(centers + (size_t)lab * FEAT);
    const float rnc = rnorms[lab];

    const float4 xv0 = xr[ln], xv1 = xr[ln + 64];
    const float4 mv0 = mr[ln], mv1 = mr[ln + 64];
    const float4 cv0 = cr[ln], cv1 = cr[ln + 64];

    float ssx = xv0.x*xv0.x + xv0.y*xv0.y + xv0.z*xv0.z + xv0.w*xv0.w
              + xv1.x*xv1.x + xv1.y*xv1.y + xv1.z*xv1.z + xv1.w*xv1.w;
    float dxm = xv0.x*mv0.x + xv0.y*mv0.y + xv0.z*mv0.z + xv0.w*mv0.w
              + xv1.x*mv1.x + xv1.y*mv1.y + xv1.z*mv1.z + xv1.w*mv1.w;
    float dxc = xv0.x*cv0.x + xv0.y*cv0.y + xv0.z*cv0.z + xv0.w*cv0.w
              + xv1.x*cv1.x + xv1.y*cv1.y + xv1.z*cv1.z + xv1.w*cv1.w;

    #pragma unroll
    for (int o = 32; o > 0; o >>= 1) {
        ssx += __shfl_xor(ssx, o, 64);
        dxm += __shfl_xor(dxm, o, 64);
        dxc += __shfl_xor(dxc, o, 64);
    }

    __shared__ float t1s[4], t2s[4];
    if (ln == 0) {
        const float rnx = 1.f / fmaxf(sqrtf(ssx), EPS_N);
        const float s_all = dxm * rnx;
        const float s_lab = dxc * rnx * rnc;
        const float e_all = expf(s_all);
        const float kC    = (float)((double)(C_CLASSES + 1) / (double)C_CLASSES);
        const float t1 = (e_all - expf(s_lab * kC));                        // / ALPHA1 (=1)
        const float t2 = -fabsf((e_all - expf(s_lab) + 0.2f) * (1.f / 50.f));
        t1s[wid] = t1;
        t2s[wid] = t2;
    }
    __syncthreads();
    if (threadIdx.x == 0) {
        lpart[(size_t)blockIdx.x * 2]     = t1s[0] + t1s[1] + t1s[2] + t1s[3];
        lpart[(size_t)blockIdx.x * 2 + 1] = t2s[0] + t2s[1] + t2s[2] + t2s[3];
    }
}

// ---------------- Kernel D: final reduction + blend ----------------
__global__ void final_loss(const float* __restrict__ lpart, int n,
                           const int* __restrict__ epoch,
                           float* __restrict__ out)
{
    __shared__ double sh1[256];
    __shared__ double sh2[256];
    double s1 = 0.0, s2 = 0.0;
    for (int i = threadIdx.x; i < n; i += blockDim.x) {
        s1 += (double)lpart[(size_t)i * 2];
        s2 += (double)lpart[(size_t)i * 2 + 1];
    }
    sh1[threadIdx.x] = s1;
    sh2[threadIdx.x] = s2;
    __syncthreads();
    for (int s = 128; s > 0; s >>= 1) {
        if (threadIdx.x < s) {
            sh1[threadIdx.x] += sh1[threadIdx.x + s];
            sh2[threadIdx.x] += sh2[threadIdx.x + s];
        }
        __syncthreads();
    }
    if (threadIdx.x == 0) {
        const float v  = fminf((float)(*epoch) * (1.f / 14.f), 1.f);
        const float l1 = (float)(sh1[0] / (double)BATCH_N);
        const float l2 = (float)(sh2[0] / (double)BATCH_N);
        out[0] = (1.f - v) * l1 + v * l2;
    }
}

extern "C" void kernel_launch(void* const* d_in, const int* in_sizes, int n_in,
                              void* d_out, int out_size, void* d_ws, size_t ws_size,
                              hipStream_t stream)
{
    const float* x       = (const float*)d_in[0];
    const int*   labels  = (const int*)d_in[1];
    // d_in[2] = ori_labels (unused by reference)
    const int*   epoch   = (const int*)d_in[3];
    const float* centers = (const float*)d_in[4];
    float* out = (float*)d_out;

    float* ws       = (float*)d_ws;
    float* mean     = ws;                       // 512
    float* partial2 = ws + 512;                 // 32*512
    float* lpart    = ws + 512 + 16384;         // (BATCH_N/4)*2
    float* rnorms   = ws + 512 + 16384 + 16384; // C_CLASSES (100000, pad to 100352)
    float* cpart    = rnorms + 100352;          // nblkA * 512

    const size_t fixed_bytes = (size_t)(512 + 16384 + 16384 + 100352) * sizeof(float);
    int nblkA = 2048;
    if (ws_size < fixed_bytes + (size_t)nblkA * FEAT * sizeof(float)) {
        size_t avail = (ws_size > fixed_bytes) ? (ws_size - fixed_bytes) : 0;
        nblkA = (int)(avail / (FEAT * sizeof(float)));
        if (nblkA < 1) nblkA = 1;
    }

    centers_pass<<<nblkA, 256, 0, stream>>>(centers, out + 1, cpart, rnorms);
    reduce_mean_s1<<<32, 512, 0, stream>>>(cpart, nblkA, partial2);
    reduce_mean_s2<<<1, 512, 0, stream>>>(partial2, 32, mean);
    row_loss<<<BATCH_N / 4, 256, 0, stream>>>(x, labels, centers, mean, rnorms, lpart);
    final_loss<<<1, 256, 0, stream>>>(lpart, BATCH_N / 4, epoch, out);
}

// Round 8
// 130.774 us; speedup vs baseline: 3.6398x; 1.0333x over previous
//
#include <hip/hip_runtime.h>
#include <math.h>

#define C_CLASSES 100000
#define FEAT      512
#define BATCH_N   32768
#define EPS_N     1e-12f

// ---------------- Kernel A: wave-per-row normalize-accumulate + ALIGNED copy ----------------
// Copy target is d_out+1 (4B misaligned). We instead store the ALIGNED out-dword
// range [row*512, row*512+512), whose values are centers[g-1], built in-register:
//   up   = __shfl_up(c[k], 1)            (lane ln gets lane ln-1's value)
//   tail = k==0 ? centers[rbase-1] : __shfl(c[k-1], 63)
// ALL shuffles execute with full exec mask (R7 bug: ds_bpermute from an inactive
// lane returns undefined/0), selection happens per-lane afterwards.
// out[0] is the loss slot (skipped); the final out dword is written by final_loss.
__global__ void __launch_bounds__(256) centers_pass(
    const float* __restrict__ centers,
    float* __restrict__ out,           // d_out (dword-aligned base!)
    float* __restrict__ cpart,         // [gridDim.x * 512]
    float* __restrict__ rnorms)        // [C_CLASSES]
{
    const int t   = threadIdx.x;
    const int wid = t >> 6;
    const int ln  = t & 63;
    const int nb  = gridDim.x;

    float acc[8] = {0.f,0.f,0.f,0.f,0.f,0.f,0.f,0.f};

    for (int row = blockIdx.x * 4 + wid; row < C_CLASSES; row += nb * 4) {
        const size_t rbase = (size_t)row * FEAT;
        const float* rp = centers + rbase;

        float c[8];
        #pragma unroll
        for (int k = 0; k < 8; ++k) c[k] = rp[ln + 64 * k];

        // previous row's last dword, loaded by ALL lanes (uniform broadcast)
        const float prev_row = (row > 0) ? centers[rbase - 1] : 0.f;

        float ss = 0.f;
        #pragma unroll
        for (int k = 0; k < 8; ++k) ss += c[k] * c[k];
        #pragma unroll
        for (int o = 32; o > 0; o >>= 1) ss += __shfl_xor(ss, o, 64);

        const float rn = 1.f / fmaxf(sqrtf(ss), EPS_N);
        if (ln == 0) rnorms[row] = rn;

        #pragma unroll
        for (int k = 0; k < 8; ++k) acc[k] += c[k] * rn;

        // shifted, aligned stores: out[rbase + ln + 64k] = centers[rbase + ln + 64k - 1]
        float* op = out + rbase;
        #pragma unroll
        for (int k = 0; k < 8; ++k) {
            const float up   = __shfl_up(c[k], 1, 64);                     // full exec
            const float tail = (k == 0) ? prev_row : __shfl(c[k - 1], 63, 64); // full exec
            const float s = (ln == 0) ? tail : up;
            if (!(row == 0 && k == 0 && ln == 0))   // out[0] is the loss slot
                op[ln + 64 * k] = s;
        }
    }

    __shared__ float accsh[4][FEAT];
    #pragma unroll
    for (int k = 0; k < 8; ++k) accsh[wid][ln + 64 * k] = acc[k];
    __syncthreads();

    #pragma unroll
    for (int j = t; j < FEAT; j += 256)
        cpart[(size_t)blockIdx.x * FEAT + j] =
            accsh[0][j] + accsh[1][j] + accsh[2][j] + accsh[3][j];
}

// ---------------- Kernel B1: parallel partial reduce over cpart blocks ----------------
__global__ void __launch_bounds__(512) reduce_mean_s1(
    const float* __restrict__ cpart, int nblk,
    float* __restrict__ partial2)
{
    const int j = threadIdx.x;             // feature
    float s = 0.f;
    for (int b = blockIdx.x; b < nblk; b += gridDim.x)
        s += cpart[(size_t)b * FEAT + j];
    partial2[(size_t)blockIdx.x * FEAT + j] = s;
}

// ---------------- Kernel B2: finish -> mean[512] ----------------
__global__ void __launch_bounds__(512) reduce_mean_s2(
    const float* __restrict__ partial2, int np,
    float* __restrict__ mean)
{
    const int j = threadIdx.x;
    float s = 0.f;
    for (int p = 0; p < np; ++p)
        s += partial2[(size_t)p * FEAT + j];
    mean[j] = s / (float)C_CLASSES;
}

// ---------------- Kernel C: per-x-row loss terms (one wave per row) ----------------
__global__ void __launch_bounds__(256) row_loss(
    const float* __restrict__ x,
    const int*   __restrict__ labels,
    const float* __restrict__ centers,
    const float* __restrict__ mean,
    const float* __restrict__ rnorms,
    float* __restrict__ lpart)          // [gridDim.x * 2]
{
    const int wid = threadIdx.x >> 6;
    const int ln  = threadIdx.x & 63;
    const int row = blockIdx.x * 4 + wid;

    const float4* __restrict__ xr = reinterpret_cast<const float4*>(x + (size_t)row * FEAT);
    const float4* __restrict__ mr = reinterpret_cast<const float4*>(mean);
    const int lab = labels[row];
    const float4* __restrict__ cr = reinterpret_cast<const float4*>(centers + (size_t)lab * FEAT);
    const float rnc = rnorms[lab];

    const float4 xv0 = xr[ln], xv1 = xr[ln + 64];
    const float4 mv0 = mr[ln], mv1 = mr[ln + 64];
    const float4 cv0 = cr[ln], cv1 = cr[ln + 64];

    float ssx = xv0.x*xv0.x + xv0.y*xv0.y + xv0.z*xv0.z + xv0.w*xv0.w
              + xv1.x*xv1.x + xv1.y*xv1.y + xv1.z*xv1.z + xv1.w*xv1.w;
    float dxm = xv0.x*mv0.x + xv0.y*mv0.y + xv0.z*mv0.z + xv0.w*mv0.w
              + xv1.x*mv1.x + xv1.y*mv1.y + xv1.z*mv1.z + xv1.w*mv1.w;
    float dxc = xv0.x*cv0.x + xv0.y*cv0.y + xv0.z*cv0.z + xv0.w*cv0.w
              + xv1.x*cv1.x + xv1.y*cv1.y + xv1.z*cv1.z + xv1.w*cv1.w;

    #pragma unroll
    for (int o = 32; o > 0; o >>= 1) {
        ssx += __shfl_xor(ssx, o, 64);
        dxm += __shfl_xor(dxm, o, 64);
        dxc += __shfl_xor(dxc, o, 64);
    }

    __shared__ float t1s[4], t2s[4];
    if (ln == 0) {
        const float rnx = 1.f / fmaxf(sqrtf(ssx), EPS_N);
        const float s_all = dxm * rnx;
        const float s_lab = dxc * rnx * rnc;
        const float e_all = expf(s_all);
        const float kC    = (float)((double)(C_CLASSES + 1) / (double)C_CLASSES);
        const float t1 = (e_all - expf(s_lab * kC));                        // / ALPHA1 (=1)
        const float t2 = -fabsf((e_all - expf(s_lab) + 0.2f) * (1.f / 50.f));
        t1s[wid] = t1;
        t2s[wid] = t2;
    }
    __syncthreads();
    if (threadIdx.x == 0) {
        lpart[(size_t)blockIdx.x * 2]     = t1s[0] + t1s[1] + t1s[2] + t1s[3];
        lpart[(size_t)blockIdx.x * 2 + 1] = t2s[0] + t2s[1] + t2s[2] + t2s[3];
    }
}

// ---------------- Kernel D: final reduction + blend + copy tail ----------------
__global__ void final_loss(const float* __restrict__ lpart, int n,
                           const int* __restrict__ epoch,
                           const float* __restrict__ centers,
                           float* __restrict__ out)
{
    __shared__ double sh1[256];
    __shared__ double sh2[256];
    double s1 = 0.0, s2 = 0.0;
    for (int i = threadIdx.x; i < n; i += blockDim.x) {
        s1 += (double)lpart[(size_t)i * 2];
        s2 += (double)lpart[(size_t)i * 2 + 1];
    }
    sh1[threadIdx.x] = s1;
    sh2[threadIdx.x] = s2;
    __syncthreads();
    for (int s = 128; s > 0; s >>= 1) {
        if (threadIdx.x < s) {
            sh1[threadIdx.x] += sh1[threadIdx.x + s];
            sh2[threadIdx.x] += sh2[threadIdx.x + s];
        }
        __syncthreads();
    }
    if (threadIdx.x == 0) {
        const float v  = fminf((float)(*epoch) * (1.f / 14.f), 1.f);
        const float l1 = (float)(sh1[0] / (double)BATCH_N);
        const float l2 = (float)(sh2[0] / (double)BATCH_N);
        out[0] = (1.f - v) * l1 + v * l2;
    }
    if (threadIdx.x == 1) {
        // last copy dword not covered by the shifted store pattern
        const size_t g = (size_t)C_CLASSES * FEAT;
        out[g] = centers[g - 1];
    }
}

extern "C" void kernel_launch(void* const* d_in, const int* in_sizes, int n_in,
                              void* d_out, int out_size, void* d_ws, size_t ws_size,
                              hipStream_t stream)
{
    const float* x       = (const float*)d_in[0];
    const int*   labels  = (const int*)d_in[1];
    // d_in[2] = ori_labels (unused by reference)
    const int*   epoch   = (const int*)d_in[3];
    const float* centers = (const float*)d_in[4];
    float* out = (float*)d_out;

    float* ws       = (float*)d_ws;
    float* mean     = ws;                       // 512
    float* partial2 = ws + 512;                 // 32*512
    float* lpart    = ws + 512 + 16384;         // (BATCH_N/4)*2
    float* rnorms   = ws + 512 + 16384 + 16384; // C_CLASSES (100000, pad to 100352)
    float* cpart    = rnorms + 100352;          // nblkA * 512

    const size_t fixed_bytes = (size_t)(512 + 16384 + 16384 + 100352) * sizeof(float);
    int nblkA = 2048;
    if (ws_size < fixed_bytes + (size_t)nblkA * FEAT * sizeof(float)) {
        size_t avail = (ws_size > fixed_bytes) ? (ws_size - fixed_bytes) : 0;
        nblkA = (int)(avail / (FEAT * sizeof(float)));
        if (nblkA < 1) nblkA = 1;
    }

    centers_pass<<<nblkA, 256, 0, stream>>>(centers, out, cpart, rnorms);
    reduce_mean_s1<<<32, 512, 0, stream>>>(cpart, nblkA, partial2);
    reduce_mean_s2<<<1, 512, 0, stream>>>(partial2, 32, mean);
    row_loss<<<BATCH_N / 4, 256, 0, stream>>>(x, labels, centers, mean, rnorms, lpart);
    final_loss<<<1, 256, 0, stream>>>(lpart, BATCH_N / 4, epoch, centers, out);
}